// Round 18
// baseline (311.611 us; speedup 1.0000x reference)
//
#include <hip/hip_runtime.h>
#include <hip/hip_bf16.h>

typedef unsigned short u16;
typedef __attribute__((ext_vector_type(8))) short bf16x8;
typedef __attribute__((ext_vector_type(4))) float f32x4;
typedef __attribute__((ext_vector_type(4))) unsigned short u16x4;

#define SQ 4096
#define HQ 128
#define NCH2 115   // per batch: sum over qt3=0..15 of ceil((4*qt3+4)/5)

__device__ __forceinline__ u16 f2b(float f) {
  unsigned int u = __float_as_uint(f);
  unsigned int r = (u + 0x7fffu + ((u >> 16) & 1u)) >> 16;  // RNE bf16
  return (u16)r;
}

__device__ __forceinline__ u16 f2b_fast(float f) {
  __hip_bfloat16 h = __float2bfloat16(f);
  return __builtin_bit_cast(u16, h);
}

__device__ __forceinline__ float b2f(u16 v) {
  unsigned int u = ((unsigned int)v) << 16;
  return __uint_as_float(u);
}

__device__ __forceinline__ void gload_lds16(const void* gsrc, void* ldst) {
  __builtin_amdgcn_global_load_lds((const __attribute__((address_space(1))) void*)gsrc,
                                   (__attribute__((address_space(3))) void*)ldst, 16, 0, 0);
}

// Wt[z][n][k] = W_z[k][n]  (bf16, B^T layout for MFMA B-frags)
__global__ __launch_bounds__(256) void k_wt(const float* __restrict__ Wq, const float* __restrict__ Wk,
                                            const float* __restrict__ Wv, u16* __restrict__ wt) {
  int idx = blockIdx.x * 256 + threadIdx.x;
  int z = idx >> 17, r = idx & 131071, n = r >> 10, k = r & 1023;
  const float* W = (z == 0) ? Wq : (z == 1) ? Wk : Wv;
  wt[idx] = f2b(W[k * 128 + n]);
}

// Fused conv+proj (R11-v4 restore, best measured ~52us): block = 64 x-rows x
// 192 cols, grid (256,2), 512 thr (8 waves 2m x 4n). x f32 3-deep prefetch ->
// in-register cvt -> swizzled LDS; W via global_load_lds, dbuf, 1 barrier/iter.
__global__ __launch_bounds__(512, 4) void k_proj(const float* __restrict__ x, const u16* __restrict__ wt,
                                                 u16* __restrict__ qb, u16* __restrict__ kb,
                                                 u16* __restrict__ vt) {
  int mt = blockIdx.x, nh = blockIdx.y;
  int t = threadIdx.x;
  int w = t >> 6, lane = t & 63;
  int wm = w >> 2, wn = w & 3;
  int lr = lane & 15, lg = lane >> 4;

  __shared__ __align__(16) u16 xl[2][64 * 32];    // 2 x 4 KB
  __shared__ __align__(16) u16 wl[2][192 * 32];   // 2 x 12 KB

  int srow = t >> 3, sc8 = t & 7;
  const float* xg = x + (long)(mt * 64 + srow) * 1024 + sc8 * 4;
  int xch = ((sc8 >> 1) ^ ((srow >> 1) & 3));
  int xoff = srow * 32 + xch * 8 + (sc8 & 1) * 4;

  f32x4 acc[2][3];
#pragma unroll
  for (int i = 0; i < 2; ++i)
#pragma unroll
    for (int j = 0; j < 3; ++j) acc[i][j] = (f32x4){0.f, 0.f, 0.f, 0.f};

  const u16* wbase = wt + (long)(nh * 192) * 1024;

  auto stage_w = [&](int bufi, int k0) {
#pragma unroll
    for (int i = 0; i < 2; ++i) {
      int ci = i * 512 + t;
      if (ci < 768) {
        int row = ci >> 2, ch = ci & 3;
        gload_lds16(wbase + (long)row * 1024 + k0 + ((ch ^ ((row >> 1) & 3)) << 3),
                    &wl[bufi][0] + ci * 8);
      }
    }
  };

  {
    float4 a0 = *(const float4*)(xg);
    stage_w(0, 0);
    u16x4 o;
    o[0] = f2b_fast(a0.x); o[1] = f2b_fast(a0.y); o[2] = f2b_fast(a0.z); o[3] = f2b_fast(a0.w);
    *(u16x4*)(&xl[0][0] + xoff) = o;
  }
  float4 p0 = *(const float4*)(xg + 32);
  float4 p1 = *(const float4*)(xg + 64);
  __syncthreads();

  for (int ks = 0; ks < 32; ++ks) {
    int cur = ks & 1;
    float4 p2;
    if (ks + 3 < 32) p2 = *(const float4*)(xg + (ks + 3) * 32);
    if (ks + 1 < 32) {
      stage_w(cur ^ 1, (ks + 1) * 32);
      u16x4 o;
      o[0] = f2b_fast(p0.x); o[1] = f2b_fast(p0.y); o[2] = f2b_fast(p0.z); o[3] = f2b_fast(p0.w);
      *(u16x4*)(&xl[cur ^ 1][0] + xoff) = o;
    }
    bf16x8 af[2], bfr[3];
#pragma unroll
    for (int i = 0; i < 2; ++i) {
      int row = wm * 32 + i * 16 + lr;
      af[i] = *(const bf16x8*)(&xl[cur][0] + row * 32 + ((lg ^ ((row >> 1) & 3)) << 3));
    }
#pragma unroll
    for (int j = 0; j < 3; ++j) {
      int row = wn * 48 + j * 16 + lr;
      bfr[j] = *(const bf16x8*)(&wl[cur][0] + row * 32 + ((lg ^ ((row >> 1) & 3)) << 3));
    }
#pragma unroll
    for (int i = 0; i < 2; ++i)
#pragma unroll
      for (int j = 0; j < 3; ++j)
        acc[i][j] = __builtin_amdgcn_mfma_f32_16x16x32_bf16(af[i], bfr[j], acc[i][j], 0, 0, 0);
    p0 = p1; p1 = p2;
    __syncthreads();
  }

#pragma unroll
  for (int i = 0; i < 2; ++i)
#pragma unroll
    for (int j = 0; j < 3; ++j)
#pragma unroll
      for (int r = 0; r < 4; ++r) {
        int m = mt * 64 + wm * 32 + i * 16 + lg * 4 + r;
        int col = nh * 192 + wn * 48 + j * 16 + lr;
        int z = col >> 7, cz = col & 127;
        u16 v = f2b(acc[i][j][r]);
        if (z == 0) qb[(long)m * 128 + cz] = v;
        else if (z == 1) kb[(long)m * 128 + cz] = v;
        else { int bb = m >> 12, sR = m & 4095; vt[(long)bb * 524288 + (long)cz * 4096 + sR] = v; }
      }
}

// flash attention v9: 8 waves x 32 q-rows (QBLK=256) -> 2x MFMA per LDS byte,
// half the tile-visits. KVBLK=64, split-K chunks of 5 key-tiles (460 blocks).
// P handled per 32-key half via small plds [8][32x32] (consistent XOR invol).
// Fixed-max softmax, ones-MFMA row-sum, T5 setprio, bf16 partials.
__global__ __launch_bounds__(512, 4) void k_attn(const u16* __restrict__ qb, const u16* __restrict__ kb,
                                                 const u16* __restrict__ vt, const int* __restrict__ kmask,
                                                 u16* __restrict__ po, float* __restrict__ pl) {
  const float SCALE_LOG2 = 0.08838834764831845f * 1.4426950408889634f;
  const float MFIX = 24.0f;
  int f = (NCH2 - 1) - (int)blockIdx.x;   // long chunks first
  int b = blockIdx.y;
  // decode f -> (qt3, kc): nch(q) = ceil((4q+4)/5) = (4q+8)/5
  int qt3 = 0, cum = 0;
  while (cum + ((4 * qt3 + 8) / 5) <= f) { cum += (4 * qt3 + 8) / 5; ++qt3; }
  int kc = f - cum;
  int ntile = 4 * qt3 + 4;
  int kt0 = kc * 5;
  int kt1 = min(kt0 + 5, ntile);

  int t = threadIdx.x, w = t >> 6, lane = t & 63;
  int lr = lane & 15, lg = lane >> 4, sw = lr & 7;
  int qrow0 = qt3 * 256 + w * 32;
  const u16* Q = qb + ((long)(b * SQ + qrow0)) * HQ;
  const u16* K = kb + (long)b * SQ * HQ;
  const u16* V = vt + (long)b * HQ * SQ;   // V^T: [128][SQ]
  const int* msk = kmask + b * SQ;

  __shared__ __align__(16) u16 Kl[2][64 * 128];   // 2 x 16 KB
  __shared__ __align__(16) u16 Vl[2][128 * 64];   // 2 x 16 KB
  __shared__ __align__(16) u16 plds[8][32 * 32];  // 16 KB

  bf16x8 aq[2][4];
#pragma unroll
  for (int i = 0; i < 2; ++i)
#pragma unroll
    for (int c = 0; c < 4; ++c)
      aq[i][c] = *(const bf16x8*)(Q + (i * 16 + lr) * HQ + c * 32 + lg * 8);

  bf16x8 ones;
#pragma unroll
  for (int e = 0; e < 8; ++e) ones[e] = (short)0x3F80;

  f32x4 o[2][8];
#pragma unroll
  for (int i = 0; i < 2; ++i)
#pragma unroll
    for (int n = 0; n < 8; ++n) o[i][n] = (f32x4){0.f, 0.f, 0.f, 0.f};
  f32x4 l_acc[2];
  l_acc[0] = (f32x4){0.f, 0.f, 0.f, 0.f};
  l_acc[1] = (f32x4){0.f, 0.f, 0.f, 0.f};

  auto stage = [&](int bufi, int kb0) {
    const u16* Kg = K + (long)kb0 * HQ;
    const u16* Vg = V + kb0;
#pragma unroll
    for (int i = 0; i < 2; ++i) {
      int ci = w * 2 + i;
      int o16 = ci * 64 + lane;
      int row = o16 >> 4, ch = o16 & 15;
      gload_lds16(Kg + row * HQ + ((ch ^ (row & 7)) << 3), &Kl[bufi][ci * 512]);
    }
#pragma unroll
    for (int i = 0; i < 2; ++i) {
      int ci = w * 2 + i;
      int o16 = ci * 64 + lane;
      int row = o16 >> 3, ch = o16 & 7;
      gload_lds16(Vg + (long)row * SQ + ((ch ^ (row & 7)) << 3), &Vl[bufi][ci * 512]);
    }
  };

  stage(0, kt0 * 64);
  __syncthreads();

  u16* pw = &plds[w][0];
  int aswz0 = lg ^ (lr & 3) ^ ((lr >> 2) & 3);    // ap read swizzle (row = i*16+lr)
  for (int kt = kt0; kt < kt1; ++kt) {
    int cur = (kt - kt0) & 1;
    int kb0 = kt * 64;
    if (kt + 1 < kt1) stage(cur ^ 1, kb0 + 64);

    if (kb0 <= qrow0 + 31) {                 // wave-uniform: any valid keys?
      float mf[4];
#pragma unroll
      for (int h = 0; h < 4; ++h) mf[h] = (msk[kb0 + h * 16 + lr] != 0) ? 1.0f : 0.0f;
      bool needc = (kb0 + 63 > qrow0);
#pragma unroll
      for (int hp = 0; hp < 2; ++hp) {
        // ---- QK^T for 32-key half: 16 MFMAs; then P -> plds
#pragma unroll
        for (int hh = 0; hh < 2; ++hh) {
          int h = hp * 2 + hh;
          const u16* Kp = &Kl[cur][(h * 16 + lr) * 128];
          bf16x8 bk[4];
#pragma unroll
          for (int c = 0; c < 4; ++c)
            bk[c] = *(const bf16x8*)(Kp + (((c * 4 + lg) ^ sw) << 3));
          f32x4 s[2];
          __builtin_amdgcn_s_setprio(1);
#pragma unroll
          for (int i = 0; i < 2; ++i) {
            f32x4 acc = (f32x4){0.f, 0.f, 0.f, 0.f};
#pragma unroll
            for (int c = 0; c < 4; ++c)
              acc = __builtin_amdgcn_mfma_f32_16x16x32_bf16(aq[i][c], bk[c], acc, 0, 0, 0);
            s[i] = acc;
          }
          __builtin_amdgcn_s_setprio(0);
#pragma unroll
          for (int i = 0; i < 2; ++i)
#pragma unroll
            for (int r = 0; r < 4; ++r) {
              int row = i * 16 + lg * 4 + r;
              int qr = qrow0 + row;
              float p = __builtin_exp2f(fmaf(s[i][r], SCALE_LOG2, -MFIX)) * mf[h];
              if (needc) p = ((kb0 + h * 16 + lr) <= qr) ? p : 0.0f;
              int chs = (hh * 2 + (lr >> 3)) ^ (row & 3) ^ ((row >> 2) & 3);
              pw[row * 32 + chs * 8 + (lr & 7)] = f2b_fast(p);
            }
        }
        // ---- P frags; l; PV for this half (16 MFMAs)
        bf16x8 ap0 = *(const bf16x8*)(pw + lr * 32 + (aswz0 << 3));
        bf16x8 ap1 = *(const bf16x8*)(pw + (16 + lr) * 32 + (aswz0 << 3));
        __builtin_amdgcn_s_setprio(1);
        l_acc[0] = __builtin_amdgcn_mfma_f32_16x16x32_bf16(ap0, ones, l_acc[0], 0, 0, 0);
        l_acc[1] = __builtin_amdgcn_mfma_f32_16x16x32_bf16(ap1, ones, l_acc[1], 0, 0, 0);
#pragma unroll
        for (int n = 0; n < 8; ++n) {
          bf16x8 bv = *(const bf16x8*)(&Vl[cur][(n * 16 + lr) * 64 + (((hp * 4 + lg) ^ sw) << 3)]);
          o[0][n] = __builtin_amdgcn_mfma_f32_16x16x32_bf16(ap0, bv, o[0][n], 0, 0, 0);
          o[1][n] = __builtin_amdgcn_mfma_f32_16x16x32_bf16(ap1, bv, o[1][n], 0, 0, 0);
        }
        __builtin_amdgcn_s_setprio(0);
      }
    }
    __syncthreads();
  }

  // ---- write partials (bf16 O [256][128], f32 l [256])
  long p = (long)b * NCH2 + f;
  u16* pob = po + p * 32768;
#pragma unroll
  for (int i = 0; i < 2; ++i)
#pragma unroll
    for (int n = 0; n < 8; ++n)
#pragma unroll
      for (int r = 0; r < 4; ++r)
        pob[(w * 32 + i * 16 + lg * 4 + r) * 128 + n * 16 + lr] = f2b_fast(o[i][n][r]);
  if (lr == 0) {
#pragma unroll
    for (int i = 0; i < 2; ++i)
#pragma unroll
      for (int r = 0; r < 4; ++r)
        pl[p * 256 + w * 32 + i * 16 + lg * 4 + r] = l_acc[i][r];
  }
}

// merge: out[b, qt3*256+row, :] = sum_i po[i] / sum_i pl[i]
__global__ __launch_bounds__(256) void k_merge(const u16* __restrict__ po, const float* __restrict__ pl,
                                               float* __restrict__ out) {
  int bx = blockIdx.x, b = blockIdx.y;
  int qt3 = bx >> 1, half = bx & 1;
  int nch = (4 * qt3 + 8) / 5;
  int pre = 0;
  for (int q = 0; q < qt3; ++q) pre += (4 * q + 8) / 5;
  long pbase = (long)b * NCH2 + pre;
  int t = threadIdx.x;
  int row = half * 128 + (t >> 1), c0 = (t & 1) * 64;
  float l = 0.f;
  for (int i = 0; i < nch; ++i) l += pl[(pbase + i) * 256 + row];
  float inv = 1.0f / l;
  const u16* p0 = po + pbase * 32768 + row * 128 + c0;
  float* orow = out + ((long)(b * SQ + qt3 * 256 + row)) * HQ + c0;
#pragma unroll
  for (int j = 0; j < 64; j += 4) {
    float acc0 = 0.f, acc1 = 0.f, acc2 = 0.f, acc3 = 0.f;
    for (int i = 0; i < nch; ++i) {
      u16x4 v = *(const u16x4*)(p0 + (long)i * 32768 + j);
      acc0 += b2f(v[0]); acc1 += b2f(v[1]); acc2 += b2f(v[2]); acc3 += b2f(v[3]);
    }
    float4 r = {acc0 * inv, acc1 * inv, acc2 * inv, acc3 * inv};
    *(float4*)(orow + j) = r;
  }
}

extern "C" void kernel_launch(void* const* d_in, const int* in_sizes, int n_in,
                              void* d_out, int out_size, void* d_ws, size_t ws_size,
                              hipStream_t stream) {
  const float* x  = (const float*)d_in[0];
  const float* Wq = (const float*)d_in[1];
  const float* Wk = (const float*)d_in[2];
  const float* Wv = (const float*)d_in[3];
  const int* kmask = (const int*)d_in[4];
  char* ws = (char*)d_ws;
  u16* wt = (u16*)(ws + 33554432);            // 768 KB: Wt
  u16* qb = (u16*)(ws + 34340864);            // 4 MB: Q bf16
  u16* kb = (u16*)(ws + 38535168);            // 4 MB: K bf16
  u16* vt = (u16*)(ws + 42729472);            // 4 MB: V^T bf16 [4][128][4096]
  u16* po = (u16*)ws;                         // 29.5 MB partial O (bf16, 460 x 64KB)
  float* pl = (float*)(ws + 31457280);        // 471 KB partial l
  float* out = (float*)d_out;

  k_wt<<<1536, 256, 0, stream>>>(Wq, Wk, Wv, wt);
  k_proj<<<dim3(256, 2), 512, 0, stream>>>(x, wt, qb, kb, vt);
  k_attn<<<dim3(NCH2, 4), 512, 0, stream>>>(qb, kb, vt, kmask, po, pl);
  k_merge<<<dim3(32, 4), 256, 0, stream>>>(po, pl, out);
}

// Round 19
// 120.111 us; speedup vs baseline: 2.5944x; 2.5944x over previous
//
#include <hip/hip_runtime.h>
#include <hip/hip_bf16.h>

typedef unsigned short u16;
typedef __attribute__((ext_vector_type(8))) short bf16x8;
typedef __attribute__((ext_vector_type(4))) float f32x4;
typedef __attribute__((ext_vector_type(4))) unsigned short u16x4;

#define SQ 4096
#define HQ 128
#define NCHUNK 144   // per batch: sum over qt2 of ceil((qt2+1)/4), chunk = 8 key-tiles

__device__ __forceinline__ u16 f2b(float f) {
  unsigned int u = __float_as_uint(f);
  unsigned int r = (u + 0x7fffu + ((u >> 16) & 1u)) >> 16;  // RNE bf16
  return (u16)r;
}

__device__ __forceinline__ u16 f2b_fast(float f) {
  __hip_bfloat16 h = __float2bfloat16(f);
  return __builtin_bit_cast(u16, h);
}

__device__ __forceinline__ float b2f(u16 v) {
  unsigned int u = ((unsigned int)v) << 16;
  return __uint_as_float(u);
}

__device__ __forceinline__ void gload_lds16(const void* gsrc, void* ldst) {
  __builtin_amdgcn_global_load_lds((const __attribute__((address_space(1))) void*)gsrc,
                                   (__attribute__((address_space(3))) void*)ldst, 16, 0, 0);
}

// Wt[z][n][k] = W_z[k][n]  (bf16, B^T layout for MFMA B-frags)
__global__ __launch_bounds__(256) void k_wt(const float* __restrict__ Wq, const float* __restrict__ Wk,
                                            const float* __restrict__ Wv, u16* __restrict__ wt) {
  int idx = blockIdx.x * 256 + threadIdx.x;
  int z = idx >> 17, r = idx & 131071, n = r >> 10, k = r & 1023;
  const float* W = (z == 0) ? Wq : (z == 1) ? Wk : Wv;
  wt[idx] = f2b(W[k * 128 + n]);
}

// Fused conv+proj (R11-v4, best measured ~50us): block = 64 x-rows x 192 cols,
// grid (256,2), 512 thr (8 waves 2m x 4n). x f32 3-deep prefetch -> in-register
// cvt -> swizzled LDS; W via global_load_lds, dbuf, 1 barrier/iter.
__global__ __launch_bounds__(512, 4) void k_proj(const float* __restrict__ x, const u16* __restrict__ wt,
                                                 u16* __restrict__ qb, u16* __restrict__ kb,
                                                 u16* __restrict__ vt) {
  int mt = blockIdx.x, nh = blockIdx.y;
  int t = threadIdx.x;
  int w = t >> 6, lane = t & 63;
  int wm = w >> 2, wn = w & 3;
  int lr = lane & 15, lg = lane >> 4;

  __shared__ __align__(16) u16 xl[2][64 * 32];    // 2 x 4 KB
  __shared__ __align__(16) u16 wl[2][192 * 32];   // 2 x 12 KB

  int srow = t >> 3, sc8 = t & 7;
  const float* xg = x + (long)(mt * 64 + srow) * 1024 + sc8 * 4;
  int xch = ((sc8 >> 1) ^ ((srow >> 1) & 3));
  int xoff = srow * 32 + xch * 8 + (sc8 & 1) * 4;

  f32x4 acc[2][3];
#pragma unroll
  for (int i = 0; i < 2; ++i)
#pragma unroll
    for (int j = 0; j < 3; ++j) acc[i][j] = (f32x4){0.f, 0.f, 0.f, 0.f};

  const u16* wbase = wt + (long)(nh * 192) * 1024;

  auto stage_w = [&](int bufi, int k0) {
#pragma unroll
    for (int i = 0; i < 2; ++i) {
      int ci = i * 512 + t;
      if (ci < 768) {
        int row = ci >> 2, ch = ci & 3;
        gload_lds16(wbase + (long)row * 1024 + k0 + ((ch ^ ((row >> 1) & 3)) << 3),
                    &wl[bufi][0] + ci * 8);
      }
    }
  };

  {
    float4 a0 = *(const float4*)(xg);
    stage_w(0, 0);
    u16x4 o;
    o[0] = f2b_fast(a0.x); o[1] = f2b_fast(a0.y); o[2] = f2b_fast(a0.z); o[3] = f2b_fast(a0.w);
    *(u16x4*)(&xl[0][0] + xoff) = o;
  }
  float4 p0 = *(const float4*)(xg + 32);
  float4 p1 = *(const float4*)(xg + 64);
  __syncthreads();

  for (int ks = 0; ks < 32; ++ks) {
    int cur = ks & 1;
    float4 p2;
    if (ks + 3 < 32) p2 = *(const float4*)(xg + (ks + 3) * 32);
    if (ks + 1 < 32) {
      stage_w(cur ^ 1, (ks + 1) * 32);
      u16x4 o;
      o[0] = f2b_fast(p0.x); o[1] = f2b_fast(p0.y); o[2] = f2b_fast(p0.z); o[3] = f2b_fast(p0.w);
      *(u16x4*)(&xl[cur ^ 1][0] + xoff) = o;
    }
    bf16x8 af[2], bfr[3];
#pragma unroll
    for (int i = 0; i < 2; ++i) {
      int row = wm * 32 + i * 16 + lr;
      af[i] = *(const bf16x8*)(&xl[cur][0] + row * 32 + ((lg ^ ((row >> 1) & 3)) << 3));
    }
#pragma unroll
    for (int j = 0; j < 3; ++j) {
      int row = wn * 48 + j * 16 + lr;
      bfr[j] = *(const bf16x8*)(&wl[cur][0] + row * 32 + ((lg ^ ((row >> 1) & 3)) << 3));
    }
#pragma unroll
    for (int i = 0; i < 2; ++i)
#pragma unroll
      for (int j = 0; j < 3; ++j)
        acc[i][j] = __builtin_amdgcn_mfma_f32_16x16x32_bf16(af[i], bfr[j], acc[i][j], 0, 0, 0);
    p0 = p1; p1 = p2;
    __syncthreads();
  }

#pragma unroll
  for (int i = 0; i < 2; ++i)
#pragma unroll
    for (int j = 0; j < 3; ++j)
#pragma unroll
      for (int r = 0; r < 4; ++r) {
        int m = mt * 64 + wm * 32 + i * 16 + lg * 4 + r;
        int col = nh * 192 + wn * 48 + j * 16 + lr;
        int z = col >> 7, cz = col & 127;
        u16 v = f2b(acc[i][j][r]);
        if (z == 0) qb[(long)m * 128 + cz] = v;
        else if (z == 1) kb[(long)m * 128 + cz] = v;
        else { int bb = m >> 12, sR = m & 4095; vt[(long)bb * 524288 + (long)cz * 4096 + sR] = v; }
      }
}

// flash attention v6 + T5 setprio (best measured ~53us): uniform split-K
// chunks (8 key-tiles); 576 blocks. 8-wave blocks share K/V staging, QBLK=128,
// KVBLK=64, double-buffered, fixed-max softmax, ones-MFMA row-sum, bf16 partials.
__global__ __launch_bounds__(512, 4) void k_attn(const u16* __restrict__ qb, const u16* __restrict__ kb,
                                                 const u16* __restrict__ vt, const int* __restrict__ kmask,
                                                 u16* __restrict__ po, float* __restrict__ pl) {
  const float SCALE_LOG2 = 0.08838834764831845f * 1.4426950408889634f;
  const float MFIX = 24.0f;
  int f = (NCHUNK - 1) - (int)blockIdx.x;  // long chunks (big qt2) first
  int b = blockIdx.y;
  int qt2 = 0, cum = 0;
  while (cum + ((qt2 + 4) >> 2) <= f) { cum += (qt2 + 4) >> 2; ++qt2; }
  int kc = f - cum;
  int ntile = 2 * qt2 + 2;
  int kt0 = kc * 8;
  int kt1 = min(kt0 + 8, ntile);

  int t = threadIdx.x, w = t >> 6, lane = t & 63;
  int lr = lane & 15, lg = lane >> 4, sw = lr & 7;
  int qrow0 = qt2 * 128 + w * 16;
  const u16* Q = qb + ((long)(b * SQ + qrow0)) * HQ;
  const u16* K = kb + (long)b * SQ * HQ;
  const u16* V = vt + (long)b * HQ * SQ;   // V^T: [128][SQ]
  const int* msk = kmask + b * SQ;

  __shared__ __align__(16) u16 Kl[2][64 * 128];   // 2 x 16 KB
  __shared__ __align__(16) u16 Vl[2][128 * 64];   // 2 x 16 KB
  __shared__ __align__(16) u16 plds[8][16 * 64];  // 16 KB, XOR-chunk layout

  bf16x8 aq[4];
#pragma unroll
  for (int c = 0; c < 4; ++c) aq[c] = *(const bf16x8*)(Q + lr * HQ + c * 32 + lg * 8);

  bf16x8 ones;
#pragma unroll
  for (int e = 0; e < 8; ++e) ones[e] = (short)0x3F80;

  f32x4 o[8];
#pragma unroll
  for (int n = 0; n < 8; ++n) o[n] = (f32x4){0.f, 0.f, 0.f, 0.f};
  f32x4 l_acc = (f32x4){0.f, 0.f, 0.f, 0.f};

  auto stage = [&](int bufi, int kb0) {
    const u16* Kg = K + (long)kb0 * HQ;
    const u16* Vg = V + kb0;
#pragma unroll
    for (int i = 0; i < 2; ++i) {
      int ci = w * 2 + i;
      int o16 = ci * 64 + lane;
      int row = o16 >> 4, ch = o16 & 15;
      gload_lds16(Kg + row * HQ + ((ch ^ (row & 7)) << 3), &Kl[bufi][ci * 512]);
    }
#pragma unroll
    for (int i = 0; i < 2; ++i) {
      int ci = w * 2 + i;
      int o16 = ci * 64 + lane;
      int row = o16 >> 3, ch = o16 & 7;
      gload_lds16(Vg + (long)row * SQ + ((ch ^ (row & 7)) << 3), &Vl[bufi][ci * 512]);
    }
  };

  stage(0, kt0 * 64);
  __syncthreads();

  u16* pw = &plds[w][0];
  for (int kt = kt0; kt < kt1; ++kt) {
    int cur = (kt - kt0) & 1;
    int kb0 = kt * 64;
    if (kt + 1 < kt1) stage(cur ^ 1, kb0 + 64);

    if (kb0 <= qrow0 + 15) {                 // wave-uniform: any valid keys?
      f32x4 s[4];
      __builtin_amdgcn_s_setprio(1);
#pragma unroll
      for (int h = 0; h < 4; ++h) {
        f32x4 acc = (f32x4){0.f, 0.f, 0.f, 0.f};
        const u16* Kp = &Kl[cur][(h * 16 + lr) * 128];
#pragma unroll
        for (int c = 0; c < 4; ++c) {
          bf16x8 bk = *(const bf16x8*)(Kp + (((c * 4 + lg) ^ sw) << 3));
          acc = __builtin_amdgcn_mfma_f32_16x16x32_bf16(aq[c], bk, acc, 0, 0, 0);
        }
        s[h] = acc;
      }
      __builtin_amdgcn_s_setprio(0);
      float mf[4];
#pragma unroll
      for (int h = 0; h < 4; ++h) mf[h] = (msk[kb0 + h * 16 + lr] != 0) ? 1.0f : 0.0f;
      bool needc = (kb0 + 63 > qrow0);       // tile crosses diagonal for this wave
#pragma unroll
      for (int r = 0; r < 4; ++r) {
        int row = lg * 4 + r;
        int qr = qrow0 + row;
#pragma unroll
        for (int h = 0; h < 4; ++h) {
          float p = __builtin_exp2f(fmaf(s[h][r], SCALE_LOG2, -MFIX)) * mf[h];
          if (needc) p = ((kb0 + h * 16 + lr) <= qr) ? p : 0.0f;
          int poff = row * 64 + ((((h * 2 + (lr >> 3)) ^ (row & 7))) << 3) + (lr & 7);
          pw[poff] = f2b_fast(p);
        }
      }
      bf16x8 ap0 = *(const bf16x8*)(pw + lr * 64 + ((lg ^ sw) << 3));
      bf16x8 ap1 = *(const bf16x8*)(pw + lr * 64 + (((4 + lg) ^ sw) << 3));
      __builtin_amdgcn_s_setprio(1);
      l_acc = __builtin_amdgcn_mfma_f32_16x16x32_bf16(ap0, ones, l_acc, 0, 0, 0);
      l_acc = __builtin_amdgcn_mfma_f32_16x16x32_bf16(ap1, ones, l_acc, 0, 0, 0);
#pragma unroll
      for (int n = 0; n < 8; ++n) {
        const u16* Vp = &Vl[cur][(n * 16 + lr) * 64];
        bf16x8 bv0 = *(const bf16x8*)(Vp + ((lg ^ sw) << 3));
        bf16x8 bv1 = *(const bf16x8*)(Vp + (((4 + lg) ^ sw) << 3));
        o[n] = __builtin_amdgcn_mfma_f32_16x16x32_bf16(ap0, bv0, o[n], 0, 0, 0);
        o[n] = __builtin_amdgcn_mfma_f32_16x16x32_bf16(ap1, bv1, o[n], 0, 0, 0);
      }
      __builtin_amdgcn_s_setprio(0);
    }
    __syncthreads();
  }

  long p = (long)b * NCHUNK + f;
  u16* pob = po + p * 16384;  // [128][128] bf16
#pragma unroll
  for (int n = 0; n < 8; ++n)
#pragma unroll
    for (int r = 0; r < 4; ++r)
      pob[(w * 16 + lg * 4 + r) * 128 + n * 16 + lr] = f2b_fast(o[n][r]);
  if (lr == 0) {
#pragma unroll
    for (int r = 0; r < 4; ++r) pl[p * 128 + w * 16 + lg * 4 + r] = l_acc[r];
  }
}

// merge: out[b, qt2*128+row, :] = sum_i po[i] / sum_i pl[i]
__global__ __launch_bounds__(256) void k_merge(const u16* __restrict__ po, const float* __restrict__ pl,
                                               float* __restrict__ out) {
  int qt2 = blockIdx.x, b = blockIdx.y;
  int nch = (qt2 + 4) >> 2;
  int pre = 0;
  for (int q = 0; q < qt2; ++q) pre += (q + 4) >> 2;
  long pbase = (long)b * NCHUNK + pre;
  int t = threadIdx.x;
  int row = t >> 1, c0 = (t & 1) * 64;
  float l = 0.f;
  for (int i = 0; i < nch; ++i) l += pl[(pbase + i) * 128 + row];
  float inv = 1.0f / l;
  const u16* p0 = po + pbase * 16384 + row * 128 + c0;
  float* orow = out + ((long)(b * SQ + qt2 * 128 + row)) * HQ + c0;
#pragma unroll
  for (int j = 0; j < 64; j += 4) {
    float acc0 = 0.f, acc1 = 0.f, acc2 = 0.f, acc3 = 0.f;
    for (int i = 0; i < nch; ++i) {
      u16x4 v = *(const u16x4*)(p0 + (long)i * 16384 + j);
      acc0 += b2f(v[0]); acc1 += b2f(v[1]); acc2 += b2f(v[2]); acc3 += b2f(v[3]);
    }
    float4 r = {acc0 * inv, acc1 * inv, acc2 * inv, acc3 * inv};
    *(float4*)(orow + j) = r;
  }
}

extern "C" void kernel_launch(void* const* d_in, const int* in_sizes, int n_in,
                              void* d_out, int out_size, void* d_ws, size_t ws_size,
                              hipStream_t stream) {
  const float* x  = (const float*)d_in[0];
  const float* Wq = (const float*)d_in[1];
  const float* Wk = (const float*)d_in[2];
  const float* Wv = (const float*)d_in[3];
  const int* kmask = (const int*)d_in[4];
  char* ws = (char*)d_ws;
  u16* wt = (u16*)(ws + 33554432);            // 768 KB: Wt
  u16* qb = (u16*)(ws + 34340864);            // 4 MB: Q bf16
  u16* kb = (u16*)(ws + 38535168);            // 4 MB: K bf16
  u16* vt = (u16*)(ws + 42729472);            // 4 MB: V^T bf16 [4][128][4096]
  u16* po = (u16*)ws;                         // 18.9 MB partial O (bf16)
  float* pl = (float*)(ws + 31195136);        // 295 KB partial l (po-region tail)
  float* out = (float*)d_out;

  k_wt<<<1536, 256, 0, stream>>>(Wq, Wk, Wv, wt);
  k_proj<<<dim3(256, 2), 512, 0, stream>>>(x, wt, qb, kb, vt);
  k_attn<<<dim3(NCHUNK, 4), 512, 0, stream>>>(qb, kb, vt, kmask, po, pl);
  k_merge<<<dim3(32, 4), 256, 0, stream>>>(po, pl, out);
}